// Round 5
// baseline (290.892 us; speedup 1.0000x reference)
//
#include <hip/hip_runtime.h>
#include <hip/hip_bf16.h>

#define NN 10000     // nodes
#define NE 640000    // edges
#define NG 64        // graphs
#define NF 128       // feature dim (both layers)
#define NC 10        // classes
#define TM 32        // gemm row tile
#define TKC 32       // gemm k chunk

// ---------------- ws layout (bytes) ----------------
// 0        deg   (10000 int)     40000  } zeroed every launch
// 73024    coff  (10001 int)     40016
// 113040   cpos  (10000 int)     40000
// 153040   dinv  (10000 f32)     40000
// 193040   csrc  (640000 int)    2560000
// 2753040  bufA  (10000*128 f32) 5120000
// 7873040  bufB  (10000*128 f32) 5120000

// Wave-uniform detection of int64 vs int32 index buffers. For little-endian
// int64, every odd 32-bit word is the (always-zero here) high half.
__device__ __forceinline__ int detect64(const int* w, long span) {
    int lane = threadIdx.x & 63;
    long e = (long)lane * (span - 1) / 63;
    return (__ballot(w[2 * e + 1] != 0) == 0ULL) ? 1 : 0;
}

__device__ __forceinline__ int ld_idx(const void* p, long i, int is64) {
    return is64 ? (int)((const long long*)p)[i] : ((const int*)p)[i];
}

// Degree count, XCD-partitioned: blocks with blockIdx%8==g own dst range
// [g*1250,(g+1)*1250) so every deg[] cache line is atomic'd from ONE XCD
// (presumed round-robin block->XCD dispatch; perf heuristic only).
__global__ __launch_bounds__(256) void k_degree(const void* __restrict__ ei,
                                                int* __restrict__ deg) {
    int is64 = detect64((const int*)ei, NE);
    int part = blockIdx.x & 7;
    int lo = part * (NN / 8), hi = lo + (NN / 8);
    int t0 = (blockIdx.x >> 3) * blockDim.x + threadIdx.x;
    int stride = (gridDim.x >> 3) * blockDim.x;
    for (int e = t0; e < NE; e += stride) {
        int dst = ld_idx(ei, (long)NE + e, is64);
        if (dst >= lo && dst < hi) atomicAdd(&deg[dst], 1);
    }
}

// Single-block exclusive scan of deg -> csr_off / csr_pos; dinv = rsqrt(deg+1)
__global__ __launch_bounds__(1024) void k_scan(const int* __restrict__ deg,
                                               int* __restrict__ off, int* __restrict__ pos,
                                               float* __restrict__ dinv) {
    __shared__ int part[1024];
    int tid = threadIdx.x;
    const int CH = 10;              // 1024*10 >= 10000
    int base = tid * CH;
    int s = 0;
#pragma unroll
    for (int i = 0; i < CH; i++) { int id = base + i; if (id < NN) s += deg[id]; }
    part[tid] = s;
    __syncthreads();
    for (int o = 1; o < 1024; o <<= 1) {
        int add = (tid >= o) ? part[tid - o] : 0;
        __syncthreads();
        part[tid] += add;
        __syncthreads();
    }
    int run = (tid > 0) ? part[tid - 1] : 0;
#pragma unroll
    for (int i = 0; i < CH; i++) {
        int id = base + i;
        if (id < NN) { off[id] = run; pos[id] = run; run += deg[id]; }
    }
    if (tid == 0) off[NN] = part[1023];
    for (int id = tid; id < NN; id += 1024)
        dinv[id] = rsqrtf((float)deg[id] + 1.0f);
}

// CSR fill, XCD-partitioned by dst range (same mapping as k_degree): all
// writes to a given csrc line / cpos counter come from one XCD -> no
// cross-XCD line ping-pong (R4 counters showed 13 writebacks/line without).
__global__ __launch_bounds__(256) void k_fill(const void* __restrict__ ei,
                                              int* __restrict__ pos,
                                              int* __restrict__ csrc) {
    int is64 = detect64((const int*)ei, NE);
    int part = blockIdx.x & 7;
    int lo = part * (NN / 8), hi = lo + (NN / 8);
    int t0 = (blockIdx.x >> 3) * blockDim.x + threadIdx.x;
    int stride = (gridDim.x >> 3) * blockDim.x;
    for (int e = t0; e < NE; e += stride) {
        int dst = ld_idx(ei, (long)NE + e, is64);
        if (dst < lo || dst >= hi) continue;
        int src = ld_idx(ei, (long)e, is64);
        int p = atomicAdd(&pos[dst], 1);
        csrc[p] = src;
    }
}

// Y = X @ W, register-tiled. Block: 256 thr, 32 rows x 128 cols; 4x4 acc.
__global__ __launch_bounds__(256) void k_gemm(const float* __restrict__ X,
                                              const float* __restrict__ W,
                                              float* __restrict__ Y, int nrows) {
    __shared__ float sX[TKC * 36];       // 4.6 KB
    __shared__ float sW[32 * 132];       // 16.9 KB
    int tid = threadIdx.x;
    int rg = tid & 7;                    // rows rg*4 .. rg*4+3
    int cg = tid >> 3;                   // cols cg*4 .. cg*4+3 (0..31)
    int m0 = blockIdx.x * TM;
    float acc[4][4] = {{0.f}};
    for (int kc = 0; kc < NF / TKC; ++kc) {
        int k0 = kc * TKC;
        {   // stage X^T (one float4 per thread)
            int row = tid >> 3, kq = tid & 7;
            int mm = m0 + row; if (mm > nrows - 1) mm = nrows - 1;
            float4 v = *(const float4*)(X + (size_t)mm * NF + k0 + kq * 4);
            sX[(kq * 4 + 0) * 36 + row] = v.x;
            sX[(kq * 4 + 1) * 36 + row] = v.y;
            sX[(kq * 4 + 2) * 36 + row] = v.z;
            sX[(kq * 4 + 3) * 36 + row] = v.w;
        }
#pragma unroll
        for (int j = 0; j < 4; ++j) {    // stage W panels (4 float4 per thread)
            int idx = tid + 256 * j;
            int k = idx >> 5, cq = idx & 31;
            float4 v = *(const float4*)(W + (size_t)(k0 + k) * NF + cq * 4);
            *(float4*)(sW + cq * 132 + k * 4) = v;
        }
        __syncthreads();
#pragma unroll 8
        for (int k = 0; k < TKC; ++k) {
            float4 xf = *(const float4*)(sX + k * 36 + rg * 4);
            float4 wf = *(const float4*)(sW + cg * 132 + k * 4);
            acc[0][0] = fmaf(xf.x, wf.x, acc[0][0]);
            acc[0][1] = fmaf(xf.x, wf.y, acc[0][1]);
            acc[0][2] = fmaf(xf.x, wf.z, acc[0][2]);
            acc[0][3] = fmaf(xf.x, wf.w, acc[0][3]);
            acc[1][0] = fmaf(xf.y, wf.x, acc[1][0]);
            acc[1][1] = fmaf(xf.y, wf.y, acc[1][1]);
            acc[1][2] = fmaf(xf.y, wf.z, acc[1][2]);
            acc[1][3] = fmaf(xf.y, wf.w, acc[1][3]);
            acc[2][0] = fmaf(xf.z, wf.x, acc[2][0]);
            acc[2][1] = fmaf(xf.z, wf.y, acc[2][1]);
            acc[2][2] = fmaf(xf.z, wf.z, acc[2][2]);
            acc[2][3] = fmaf(xf.z, wf.w, acc[2][3]);
            acc[3][0] = fmaf(xf.w, wf.x, acc[3][0]);
            acc[3][1] = fmaf(xf.w, wf.y, acc[3][1]);
            acc[3][2] = fmaf(xf.w, wf.z, acc[3][2]);
            acc[3][3] = fmaf(xf.w, wf.w, acc[3][3]);
        }
        __syncthreads();
    }
#pragma unroll
    for (int r = 0; r < 4; ++r) {
        int m = m0 + rg * 4 + r;
        if (m < nrows)
            *(float4*)(Y + (size_t)m * NF + cg * 4) =
                make_float4(acc[r][0], acc[r][1], acc[r][2], acc[r][3]);
    }
}

// OUT[n] = relu( sum_{e in in(n)} XW[src_e]*dinv[src_e]*dinv[n]
//                + XW[n]*dinv[n]^2 + bias )
// One wave per node; half-wave per edge; float4 per lane.
__global__ __launch_bounds__(256) void k_gather(const float* __restrict__ XW,
                                                const int* __restrict__ off,
                                                const int* __restrict__ csrc,
                                                const float* __restrict__ dinv,
                                                const float* __restrict__ bias,
                                                float* __restrict__ OUT) {
    int wid = threadIdx.x >> 6, lane = threadIdx.x & 63;
    int half = lane >> 5;
    int c4 = lane & 31;
    int n = blockIdx.x * 4 + wid;
    if (n >= NN) return;
    int beg = off[n], end = off[n + 1];
    float din = dinv[n];
    float4 acc = make_float4(0.f, 0.f, 0.f, 0.f);
    int e = beg + half;
    for (; e + 2 < end; e += 4) {
        int s0 = csrc[e];
        int s1 = csrc[e + 2];
        float4 v0 = ((const float4*)(XW + (size_t)s0 * NF))[c4];
        float4 v1 = ((const float4*)(XW + (size_t)s1 * NF))[c4];
        float w0 = dinv[s0] * din;
        float w1 = dinv[s1] * din;
        acc.x = fmaf(v0.x, w0, acc.x); acc.y = fmaf(v0.y, w0, acc.y);
        acc.z = fmaf(v0.z, w0, acc.z); acc.w = fmaf(v0.w, w0, acc.w);
        acc.x = fmaf(v1.x, w1, acc.x); acc.y = fmaf(v1.y, w1, acc.y);
        acc.z = fmaf(v1.z, w1, acc.z); acc.w = fmaf(v1.w, w1, acc.w);
    }
    for (; e < end; e += 2) {
        int s = csrc[e];
        float w = dinv[s] * din;
        float4 v = ((const float4*)(XW + (size_t)s * NF))[c4];
        acc.x = fmaf(v.x, w, acc.x); acc.y = fmaf(v.y, w, acc.y);
        acc.z = fmaf(v.z, w, acc.z); acc.w = fmaf(v.w, w, acc.w);
    }
    acc.x += __shfl_xor(acc.x, 32);
    acc.y += __shfl_xor(acc.y, 32);
    acc.z += __shfl_xor(acc.z, 32);
    acc.w += __shfl_xor(acc.w, 32);
    if (half == 0) {
        float4 sv = ((const float4*)(XW + (size_t)n * NF))[c4];
        float4 bb = ((const float4*)bias)[c4];
        float d2 = din * din;
        float4 o;
        o.x = fmaxf(fmaf(sv.x, d2, acc.x) + bb.x, 0.f);
        o.y = fmaxf(fmaf(sv.y, d2, acc.y) + bb.y, 0.f);
        o.z = fmaxf(fmaf(sv.z, d2, acc.z) + bb.z, 0.f);
        o.w = fmaxf(fmaf(sv.w, d2, acc.w) + bb.w, 0.f);
        ((float4*)(OUT + (size_t)n * NF))[c4] = o;
    }
}

// Fused global-mean-pool + final linear (batch is sorted -> contiguous ranges).
__global__ __launch_bounds__(256) void k_poolfin(const float* __restrict__ H,
                                                 const void* __restrict__ batch,
                                                 const float* __restrict__ Wl,
                                                 const float* __restrict__ bl,
                                                 float* __restrict__ out) {
    int is64 = detect64((const int*)batch, NN / 2);
    __shared__ int sb[2];
    __shared__ float4 part[256];
    __shared__ float pooled[NF];
    int g = blockIdx.x;
    int tid = threadIdx.x;
    if (tid < 2) {
        int target = g + tid;                 // lower_bound(batch, target)
        int lo = 0, hi = NN;
        while (lo < hi) {
            int mid = (lo + hi) >> 1;
            if (ld_idx(batch, mid, is64) < target) lo = mid + 1; else hi = mid;
        }
        sb[tid] = lo;
    }
    __syncthreads();
    int beg = sb[0], end = sb[1];
    int c4 = tid & 31, r = tid >> 5;          // 8 rows in flight
    float4 acc = make_float4(0.f, 0.f, 0.f, 0.f);
    for (int n = beg + r; n < end; n += 8) {
        float4 v = ((const float4*)(H + (size_t)n * NF))[c4];
        acc.x += v.x; acc.y += v.y; acc.z += v.z; acc.w += v.w;
    }
    part[tid] = acc;
    __syncthreads();
    if (tid < 32) {
        float4 s = part[tid];
#pragma unroll
        for (int j = 1; j < 8; j++) {
            float4 p = part[tid + 32 * j];
            s.x += p.x; s.y += p.y; s.z += p.z; s.w += p.w;
        }
        float ic = 1.0f / fmaxf((float)(end - beg), 1.0f);
        pooled[tid * 4 + 0] = s.x * ic;
        pooled[tid * 4 + 1] = s.y * ic;
        pooled[tid * 4 + 2] = s.z * ic;
        pooled[tid * 4 + 3] = s.w * ic;
    }
    __syncthreads();
    if (tid < NC) {
        float a = bl[tid];
#pragma unroll 8
        for (int k = 0; k < NF; k++)
            a = fmaf(pooled[k], Wl[k * NC + tid], a);
        out[g * NC + tid] = a;
    }
}

extern "C" void kernel_launch(void* const* d_in, const int* in_sizes, int n_in,
                              void* d_out, int out_size, void* d_ws, size_t ws_size,
                              hipStream_t stream) {
    const float* x  = (const float*)d_in[0];
    const void*  ei = d_in[1];
    const void*  bt = d_in[2];
    const float* W1 = (const float*)d_in[3];
    const float* b1 = (const float*)d_in[4];
    const float* W2 = (const float*)d_in[5];
    const float* b2 = (const float*)d_in[6];
    const float* Wl = (const float*)d_in[7];
    const float* bl = (const float*)d_in[8];

    char* ws = (char*)d_ws;
    int*   deg   = (int*)(ws + 0);
    int*   coff  = (int*)(ws + 73024);
    int*   cpos  = (int*)(ws + 113040);
    float* dinv  = (float*)(ws + 153040);
    int*   csrc  = (int*)(ws + 193040);
    float* bufA  = (float*)(ws + 2753040);
    float* bufB  = (float*)(ws + 7873040);

    hipMemsetAsync(ws, 0, 40000, stream);   // deg only

    k_degree<<<2048, 256, 0, stream>>>(ei, deg);
    k_scan<<<1, 1024, 0, stream>>>(deg, coff, cpos, dinv);
    k_fill<<<2048, 256, 0, stream>>>(ei, cpos, csrc);

    k_gemm<<<(NN + TM - 1) / TM, 256, 0, stream>>>(x, W1, bufA, NN);
    k_gather<<<(NN + 3) / 4, 256, 0, stream>>>(bufA, coff, csrc, dinv, b1, bufB);
    k_gemm<<<(NN + TM - 1) / TM, 256, 0, stream>>>(bufB, W2, bufA, NN);
    k_gather<<<(NN + 3) / 4, 256, 0, stream>>>(bufA, coff, csrc, dinv, b2, bufB);

    k_poolfin<<<NG, 256, 0, stream>>>(bufB, bt, Wl, bl, (float*)d_out);
}

// Round 6
// 236.060 us; speedup vs baseline: 1.2323x; 1.2323x over previous
//
#include <hip/hip_runtime.h>
#include <hip/hip_bf16.h>

#define NN 10000     // nodes
#define NE 640000    // edges
#define NG 64        // graphs
#define NF 128       // feature dim (both layers)
#define NC 10        // classes
#define TM 32        // gemm row tile
#define TKC 32       // gemm k chunk
#define NB 250       // dst buckets (40 nodes each)
#define BSZ 40       // nodes per bucket
#define G1 512       // blocks in hist/bucket passes
#define ECHUNK 1250  // edges per block (G1*ECHUNK == NE)

// ---------------- ws layout (bytes) ----------------
// 0        coff  (10001 int)     40004
// 40016    bbase (251 int)       1004
// 41024    dinv  (10000 f32)     40000
// 81040    csrc  (640000 int)    2560000
// 2641040  bufA  (10000*128 f32) 5120000   [bh (512KB) aliases head: dead before gemm]
// 7761040  bufB  (10000*128 f32) 5120000   [ebuf (2.56MB) aliases head: dead before gather]
// total 12.88 MB  (zero global atomics -> nothing needs pre-zeroing)

// Wave-uniform detection of int64 vs int32 index buffers. For little-endian
// int64, every odd 32-bit word is the (always-zero here) high half.
__device__ __forceinline__ int detect64(const int* w, long span) {
    int lane = threadIdx.x & 63;
    long e = (long)lane * (span - 1) / 63;
    return (__ballot(w[2 * e + 1] != 0) == 0ULL) ? 1 : 0;
}

__device__ __forceinline__ int ld_idx(const void* p, long i, int is64) {
    return is64 ? (int)((const long long*)p)[i] : ((const int*)p)[i];
}

// Pass A: per-block bucket histogram of this block's edge chunk (LDS atomics
// only; deterministic 1KB global write per block).
__global__ __launch_bounds__(256) void k_hist(const void* __restrict__ ei,
                                              int* __restrict__ bh) {
    int is64 = detect64((const int*)ei, NE);
    __shared__ int hist[256];
    int tid = threadIdx.x;
    hist[tid] = 0;
    __syncthreads();
    int e0 = blockIdx.x * ECHUNK, e1 = min(NE, e0 + ECHUNK);
    for (int e = e0 + tid; e < e1; e += 256) {
        int dst = ld_idx(ei, (long)NE + e, is64);
        atomicAdd(&hist[dst / BSZ], 1);
    }
    __syncthreads();
    bh[blockIdx.x * 256 + tid] = hist[tid];
}

// Pass B: turn per-block bucket counts into global write cursors.
// bh[g*256+b] := bucket_base[b] + sum_{g'<g} count(b,g');  bbase[b] also out.
__global__ __launch_bounds__(1024) void k_bscan(int* __restrict__ bh,
                                                int* __restrict__ bbase) {
    __shared__ int btot[256];
    __shared__ int bb[NB + 1];
    int tid = threadIdx.x;
    if (tid < NB) {
        int run = 0;
        for (int g = 0; g < G1; ++g) {
            int v = bh[g * 256 + tid];
            bh[g * 256 + tid] = run;
            run += v;
        }
        btot[tid] = run;
    }
    __syncthreads();
    if (tid == 0) {
        int run = 0;
        for (int b = 0; b < NB; ++b) { bb[b] = run; run += btot[b]; }
        bb[NB] = run;        // == NE
    }
    __syncthreads();
    if (tid <= NB) bbase[tid] = bb[tid];
    for (int idx = tid; idx < G1 * 256; idx += 1024) {
        int b = idx & 255;
        if (b < NB) bh[idx] += bb[b];
    }
}

// Pass C: scatter edges to their bucket region, packed (ldst<<14)|src.
// Cursors in LDS (atomics local); each bucket slot written exactly once.
__global__ __launch_bounds__(256) void k_bucket(const void* __restrict__ ei,
                                                const int* __restrict__ bh,
                                                int* __restrict__ ebuf) {
    int is64 = detect64((const int*)ei, NE);
    __shared__ int cur[256];
    int tid = threadIdx.x;
    cur[tid] = bh[blockIdx.x * 256 + tid];
    __syncthreads();
    int e0 = blockIdx.x * ECHUNK, e1 = min(NE, e0 + ECHUNK);
    for (int e = e0 + tid; e < e1; e += 256) {
        int dst = ld_idx(ei, (long)NE + e, is64);
        int src = ld_idx(ei, (long)e, is64);
        int b = dst / BSZ;
        int p = atomicAdd(&cur[b], 1);
        ebuf[p] = ((dst - b * BSZ) << 14) | src;
    }
}

// Pass D: one block per bucket. Count per-dst (40 nodes) in LDS, scan ->
// coff/dinv; then in-bucket scatter csrc (block-private contiguous region).
__global__ __launch_bounds__(256) void k_csr(const int* __restrict__ ebuf,
                                             const int* __restrict__ bbase,
                                             int* __restrict__ coff,
                                             float* __restrict__ dinv,
                                             int* __restrict__ csrc) {
    __shared__ int dcount[BSZ];
    __shared__ int dstart[BSZ];
    __shared__ int cur[BSZ];
    int b = blockIdx.x, tid = threadIdx.x;
    if (tid < BSZ) dcount[tid] = 0;
    __syncthreads();
    int base = bbase[b], end = bbase[b + 1];
    for (int i = base + tid; i < end; i += 256)
        atomicAdd(&dcount[ebuf[i] >> 14], 1);
    __syncthreads();
    if (tid == 0) {
        int run = 0;
        for (int i = 0; i < BSZ; ++i) {
            dstart[i] = run; cur[i] = base + run; run += dcount[i];
        }
    }
    __syncthreads();
    if (tid < BSZ) {
        coff[b * BSZ + tid] = base + dstart[tid];
        dinv[b * BSZ + tid] = rsqrtf((float)dcount[tid] + 1.0f);
    }
    if (b == NB - 1 && tid == 0) coff[NN] = NE;
    for (int i = base + tid; i < end; i += 256) {
        int pk = ebuf[i];
        int p = atomicAdd(&cur[pk >> 14], 1);
        csrc[p] = pk & 16383;
    }
}

// Y = X @ W, register-tiled. Block: 256 thr, 32 rows x 128 cols; 4x4 acc.
__global__ __launch_bounds__(256) void k_gemm(const float* __restrict__ X,
                                              const float* __restrict__ W,
                                              float* __restrict__ Y, int nrows) {
    __shared__ float sX[TKC * 36];       // 4.6 KB
    __shared__ float sW[32 * 132];       // 16.9 KB
    int tid = threadIdx.x;
    int rg = tid & 7;                    // rows rg*4 .. rg*4+3
    int cg = tid >> 3;                   // cols cg*4 .. cg*4+3 (0..31)
    int m0 = blockIdx.x * TM;
    float acc[4][4] = {{0.f}};
    for (int kc = 0; kc < NF / TKC; ++kc) {
        int k0 = kc * TKC;
        {   // stage X^T (one float4 per thread)
            int row = tid >> 3, kq = tid & 7;
            int mm = m0 + row; if (mm > nrows - 1) mm = nrows - 1;
            float4 v = *(const float4*)(X + (size_t)mm * NF + k0 + kq * 4);
            sX[(kq * 4 + 0) * 36 + row] = v.x;
            sX[(kq * 4 + 1) * 36 + row] = v.y;
            sX[(kq * 4 + 2) * 36 + row] = v.z;
            sX[(kq * 4 + 3) * 36 + row] = v.w;
        }
#pragma unroll
        for (int j = 0; j < 4; ++j) {    // stage W panels (4 float4 per thread)
            int idx = tid + 256 * j;
            int k = idx >> 5, cq = idx & 31;
            float4 v = *(const float4*)(W + (size_t)(k0 + k) * NF + cq * 4);
            *(float4*)(sW + cq * 132 + k * 4) = v;
        }
        __syncthreads();
#pragma unroll 8
        for (int k = 0; k < TKC; ++k) {
            float4 xf = *(const float4*)(sX + k * 36 + rg * 4);
            float4 wf = *(const float4*)(sW + cg * 132 + k * 4);
            acc[0][0] = fmaf(xf.x, wf.x, acc[0][0]);
            acc[0][1] = fmaf(xf.x, wf.y, acc[0][1]);
            acc[0][2] = fmaf(xf.x, wf.z, acc[0][2]);
            acc[0][3] = fmaf(xf.x, wf.w, acc[0][3]);
            acc[1][0] = fmaf(xf.y, wf.x, acc[1][0]);
            acc[1][1] = fmaf(xf.y, wf.y, acc[1][1]);
            acc[1][2] = fmaf(xf.y, wf.z, acc[1][2]);
            acc[1][3] = fmaf(xf.y, wf.w, acc[1][3]);
            acc[2][0] = fmaf(xf.z, wf.x, acc[2][0]);
            acc[2][1] = fmaf(xf.z, wf.y, acc[2][1]);
            acc[2][2] = fmaf(xf.z, wf.z, acc[2][2]);
            acc[2][3] = fmaf(xf.z, wf.w, acc[2][3]);
            acc[3][0] = fmaf(xf.w, wf.x, acc[3][0]);
            acc[3][1] = fmaf(xf.w, wf.y, acc[3][1]);
            acc[3][2] = fmaf(xf.w, wf.z, acc[3][2]);
            acc[3][3] = fmaf(xf.w, wf.w, acc[3][3]);
        }
        __syncthreads();
    }
#pragma unroll
    for (int r = 0; r < 4; ++r) {
        int m = m0 + rg * 4 + r;
        if (m < nrows)
            *(float4*)(Y + (size_t)m * NF + cg * 4) =
                make_float4(acc[r][0], acc[r][1], acc[r][2], acc[r][3]);
    }
}

// OUT[n] = relu( sum_{e in in(n)} XW[src_e]*dinv[src_e]*dinv[n]
//                + XW[n]*dinv[n]^2 + bias )
// One wave per node; half-wave per edge; float4 per lane.
__global__ __launch_bounds__(256) void k_gather(const float* __restrict__ XW,
                                                const int* __restrict__ off,
                                                const int* __restrict__ csrc,
                                                const float* __restrict__ dinv,
                                                const float* __restrict__ bias,
                                                float* __restrict__ OUT) {
    int wid = threadIdx.x >> 6, lane = threadIdx.x & 63;
    int half = lane >> 5;
    int c4 = lane & 31;
    int n = blockIdx.x * 4 + wid;
    if (n >= NN) return;
    int beg = off[n], end = off[n + 1];
    float din = dinv[n];
    float4 acc = make_float4(0.f, 0.f, 0.f, 0.f);
    int e = beg + half;
    for (; e + 2 < end; e += 4) {
        int s0 = csrc[e];
        int s1 = csrc[e + 2];
        float4 v0 = ((const float4*)(XW + (size_t)s0 * NF))[c4];
        float4 v1 = ((const float4*)(XW + (size_t)s1 * NF))[c4];
        float w0 = dinv[s0] * din;
        float w1 = dinv[s1] * din;
        acc.x = fmaf(v0.x, w0, acc.x); acc.y = fmaf(v0.y, w0, acc.y);
        acc.z = fmaf(v0.z, w0, acc.z); acc.w = fmaf(v0.w, w0, acc.w);
        acc.x = fmaf(v1.x, w1, acc.x); acc.y = fmaf(v1.y, w1, acc.y);
        acc.z = fmaf(v1.z, w1, acc.z); acc.w = fmaf(v1.w, w1, acc.w);
    }
    for (; e < end; e += 2) {
        int s = csrc[e];
        float w = dinv[s] * din;
        float4 v = ((const float4*)(XW + (size_t)s * NF))[c4];
        acc.x = fmaf(v.x, w, acc.x); acc.y = fmaf(v.y, w, acc.y);
        acc.z = fmaf(v.z, w, acc.z); acc.w = fmaf(v.w, w, acc.w);
    }
    acc.x += __shfl_xor(acc.x, 32);
    acc.y += __shfl_xor(acc.y, 32);
    acc.z += __shfl_xor(acc.z, 32);
    acc.w += __shfl_xor(acc.w, 32);
    if (half == 0) {
        float4 sv = ((const float4*)(XW + (size_t)n * NF))[c4];
        float4 bb = ((const float4*)bias)[c4];
        float d2 = din * din;
        float4 o;
        o.x = fmaxf(fmaf(sv.x, d2, acc.x) + bb.x, 0.f);
        o.y = fmaxf(fmaf(sv.y, d2, acc.y) + bb.y, 0.f);
        o.z = fmaxf(fmaf(sv.z, d2, acc.z) + bb.z, 0.f);
        o.w = fmaxf(fmaf(sv.w, d2, acc.w) + bb.w, 0.f);
        ((float4*)(OUT + (size_t)n * NF))[c4] = o;
    }
}

// Fused global-mean-pool + final linear (batch is sorted -> contiguous ranges).
__global__ __launch_bounds__(256) void k_poolfin(const float* __restrict__ H,
                                                 const void* __restrict__ batch,
                                                 const float* __restrict__ Wl,
                                                 const float* __restrict__ bl,
                                                 float* __restrict__ out) {
    int is64 = detect64((const int*)batch, NN / 2);
    __shared__ int sb[2];
    __shared__ float4 part[256];
    __shared__ float pooled[NF];
    int g = blockIdx.x;
    int tid = threadIdx.x;
    if (tid < 2) {
        int target = g + tid;                 // lower_bound(batch, target)
        int lo = 0, hi = NN;
        while (lo < hi) {
            int mid = (lo + hi) >> 1;
            if (ld_idx(batch, mid, is64) < target) lo = mid + 1; else hi = mid;
        }
        sb[tid] = lo;
    }
    __syncthreads();
    int beg = sb[0], end = sb[1];
    int c4 = tid & 31, r = tid >> 5;          // 8 rows in flight
    float4 acc = make_float4(0.f, 0.f, 0.f, 0.f);
    for (int n = beg + r; n < end; n += 8) {
        float4 v = ((const float4*)(H + (size_t)n * NF))[c4];
        acc.x += v.x; acc.y += v.y; acc.z += v.z; acc.w += v.w;
    }
    part[tid] = acc;
    __syncthreads();
    if (tid < 32) {
        float4 s = part[tid];
#pragma unroll
        for (int j = 1; j < 8; j++) {
            float4 p = part[tid + 32 * j];
            s.x += p.x; s.y += p.y; s.z += p.z; s.w += p.w;
        }
        float ic = 1.0f / fmaxf((float)(end - beg), 1.0f);
        pooled[tid * 4 + 0] = s.x * ic;
        pooled[tid * 4 + 1] = s.y * ic;
        pooled[tid * 4 + 2] = s.z * ic;
        pooled[tid * 4 + 3] = s.w * ic;
    }
    __syncthreads();
    if (tid < NC) {
        float a = bl[tid];
#pragma unroll 8
        for (int k = 0; k < NF; k++)
            a = fmaf(pooled[k], Wl[k * NC + tid], a);
        out[g * NC + tid] = a;
    }
}

extern "C" void kernel_launch(void* const* d_in, const int* in_sizes, int n_in,
                              void* d_out, int out_size, void* d_ws, size_t ws_size,
                              hipStream_t stream) {
    const float* x  = (const float*)d_in[0];
    const void*  ei = d_in[1];
    const void*  bt = d_in[2];
    const float* W1 = (const float*)d_in[3];
    const float* b1 = (const float*)d_in[4];
    const float* W2 = (const float*)d_in[5];
    const float* b2 = (const float*)d_in[6];
    const float* Wl = (const float*)d_in[7];
    const float* bl = (const float*)d_in[8];

    char* ws = (char*)d_ws;
    int*   coff  = (int*)(ws + 0);
    int*   bbase = (int*)(ws + 40016);
    float* dinv  = (float*)(ws + 41024);
    int*   csrc  = (int*)(ws + 81040);
    float* bufA  = (float*)(ws + 2641040);
    float* bufB  = (float*)(ws + 7761040);
    int*   bh    = (int*)bufA;     // 512 KB scratch, dead before k_gemm
    int*   ebuf  = (int*)bufB;     // 2.56 MB scratch, dead before k_gather

    k_hist  <<<G1, 256, 0, stream>>>(ei, bh);
    k_bscan <<<1, 1024, 0, stream>>>(bh, bbase);
    k_bucket<<<G1, 256, 0, stream>>>(ei, bh, ebuf);
    k_csr   <<<NB, 256, 0, stream>>>(ebuf, bbase, coff, dinv, csrc);

    k_gemm<<<(NN + TM - 1) / TM, 256, 0, stream>>>(x, W1, bufA, NN);
    k_gather<<<(NN + 3) / 4, 256, 0, stream>>>(bufA, coff, csrc, dinv, b1, bufB);
    k_gemm<<<(NN + TM - 1) / TM, 256, 0, stream>>>(bufB, W2, bufA, NN);
    k_gather<<<(NN + 3) / 4, 256, 0, stream>>>(bufA, coff, csrc, dinv, b2, bufB);

    k_poolfin<<<NG, 256, 0, stream>>>(bufB, bt, Wl, bl, (float*)d_out);
}

// Round 7
// 199.800 us; speedup vs baseline: 1.4559x; 1.1815x over previous
//
#include <hip/hip_runtime.h>
#include <hip/hip_bf16.h>

#define NN 10000     // nodes
#define NE 640000    // edges
#define NG 64        // graphs
#define NF 128       // feature dim (both layers)
#define NC 10        // classes
#define TM 32        // gemm row tile
#define TKC 32       // gemm k chunk
#define NB 250       // dst buckets (40 nodes each)
#define BSZ 40       // nodes per bucket
#define G1 512       // blocks in hist/bucket passes
#define ECHUNK 1250  // edges per block (G1*ECHUNK == NE)

// ---------------- ws layout (bytes) ----------------
// 0        coff  (10001 int)     40016
// 40016    bbase (251 int)       1024
// 41040    btot  (250 int)       1024
// 42064    dinv  (10000 f32)     40000
// 82064    csrc  (640000 int)    2560000
// 2642064  cw    (640000 f32)    2560000
// 5202064  bufA  (10000*128 f32) 5120000  [bh (512KB) aliases head: dead before gemm1]
// 10322064 bufB  (10000*128 f32) 5120000  [ebuf (2.56MB) aliases head: dead before gather1]
// total ~15.4 MB; zero global atomics -> no pre-zeroing needed

// Wave-uniform detection of int64 vs int32 index buffers. For little-endian
// int64, every odd 32-bit word is the (always-zero here) high half.
__device__ __forceinline__ int detect64(const int* w, long span) {
    int lane = threadIdx.x & 63;
    long e = (long)lane * (span - 1) / 63;
    return (__ballot(w[2 * e + 1] != 0) == 0ULL) ? 1 : 0;
}

__device__ __forceinline__ int ld_idx(const void* p, long i, int is64) {
    return is64 ? (int)((const long long*)p)[i] : ((const int*)p)[i];
}

// Pass A: per-block bucket histogram, stored bucket-major: bh[b*G1 + g].
__global__ __launch_bounds__(256) void k_hist(const void* __restrict__ ei,
                                              int* __restrict__ bh) {
    int is64 = detect64((const int*)ei, NE);
    __shared__ int hist[256];
    int tid = threadIdx.x;
    hist[tid] = 0;
    __syncthreads();
    int e0 = blockIdx.x * ECHUNK, e1 = min(NE, e0 + ECHUNK);
    for (int e = e0 + tid; e < e1; e += 256) {
        int dst = ld_idx(ei, (long)NE + e, is64);
        atomicAdd(&hist[dst / BSZ], 1);
    }
    __syncthreads();
    bh[tid * G1 + blockIdx.x] = hist[tid];
}

// Pass B1: per-bucket exclusive prefix over the G1 group counts (one wave per
// bucket; 8 serial-in-lane + shfl wave scan). btot[b] = bucket total.
__global__ __launch_bounds__(256) void k_bscan1(int* __restrict__ bh,
                                                int* __restrict__ btot) {
    int w = blockIdx.x * 4 + (threadIdx.x >> 6);
    if (w >= NB) return;
    int lane = threadIdx.x & 63;
    int base = w * G1 + lane * 8;
    int vals[8];
    int lsum = 0;
#pragma unroll
    for (int i = 0; i < 8; ++i) { vals[i] = bh[base + i]; lsum += vals[i]; }
    int pref = lsum;
    for (int o = 1; o < 64; o <<= 1) {
        int t = __shfl_up(pref, o, 64);
        if (lane >= o) pref += t;
    }
    int run = pref - lsum;                  // exclusive
#pragma unroll
    for (int i = 0; i < 8; ++i) { int v = vals[i]; bh[base + i] = run; run += v; }
    if (lane == 63) btot[w] = run;
}

// Pass B2: scan 250 bucket totals -> bbase (tiny, LDS-staged).
__global__ __launch_bounds__(256) void k_bscan2(const int* __restrict__ btot,
                                                int* __restrict__ bbase) {
    __shared__ int s[256];
    int tid = threadIdx.x;
    s[tid] = (tid < NB) ? btot[tid] : 0;
    __syncthreads();
    if (tid == 0) {
        int run = 0;
        for (int b = 0; b < NB; ++b) { int v = s[b]; s[b] = run; run += v; }
    }
    __syncthreads();
    if (tid < NB) bbase[tid] = s[tid];
    if (tid == 0) bbase[NB] = NE;
}

// Pass C: scatter edges to their bucket region, packed (ldst<<14)|src.
// Cursor = in-bucket group prefix + bucket base; LDS atomics only.
__global__ __launch_bounds__(256) void k_bucket(const void* __restrict__ ei,
                                                const int* __restrict__ bh,
                                                const int* __restrict__ bbase,
                                                int* __restrict__ ebuf) {
    int is64 = detect64((const int*)ei, NE);
    __shared__ int cur[256];
    int tid = threadIdx.x;
    if (tid < NB) cur[tid] = bh[tid * G1 + blockIdx.x] + bbase[tid];
    __syncthreads();
    int e0 = blockIdx.x * ECHUNK, e1 = min(NE, e0 + ECHUNK);
    for (int e = e0 + tid; e < e1; e += 256) {
        int dst = ld_idx(ei, (long)NE + e, is64);
        int src = ld_idx(ei, (long)e, is64);
        int b = dst / BSZ;
        int p = atomicAdd(&cur[b], 1);
        ebuf[p] = ((dst - b * BSZ) << 14) | src;
    }
}

// Pass C2: per-bucket dst-degree -> dinv (needed globally before k_csr
// computes cross-node edge weights).
__global__ __launch_bounds__(256) void k_deg(const int* __restrict__ ebuf,
                                             const int* __restrict__ bbase,
                                             float* __restrict__ dinv) {
    __shared__ int dcount[BSZ];
    int b = blockIdx.x, tid = threadIdx.x;
    if (tid < BSZ) dcount[tid] = 0;
    __syncthreads();
    int base = bbase[b], end = bbase[b + 1];
    for (int i = base + tid; i < end; i += 256)
        atomicAdd(&dcount[ebuf[i] >> 14], 1);
    __syncthreads();
    if (tid < BSZ) dinv[b * BSZ + tid] = rsqrtf((float)dcount[tid] + 1.0f);
}

// Pass D: one block per bucket. Count/scan 40 dsts -> coff; scatter csrc AND
// precomputed edge weight cw = dinv[src]*dinv[dst] (block-private region).
__global__ __launch_bounds__(256) void k_csr(const int* __restrict__ ebuf,
                                             const int* __restrict__ bbase,
                                             const float* __restrict__ dinv,
                                             int* __restrict__ coff,
                                             int* __restrict__ csrc,
                                             float* __restrict__ cw) {
    __shared__ int dcount[BSZ];
    __shared__ int dstart[BSZ];
    __shared__ int cur[BSZ];
    __shared__ float dloc[BSZ];
    int b = blockIdx.x, tid = threadIdx.x;
    if (tid < BSZ) dcount[tid] = 0;
    __syncthreads();
    int base = bbase[b], end = bbase[b + 1];
    for (int i = base + tid; i < end; i += 256)
        atomicAdd(&dcount[ebuf[i] >> 14], 1);
    __syncthreads();
    if (tid == 0) {
        int run = 0;
        for (int i = 0; i < BSZ; ++i) {
            dstart[i] = run; cur[i] = base + run; run += dcount[i];
        }
    }
    __syncthreads();
    if (tid < BSZ) {
        coff[b * BSZ + tid] = base + dstart[tid];
        dloc[tid] = dinv[b * BSZ + tid];
    }
    if (b == NB - 1 && tid == 0) coff[NN] = NE;
    __syncthreads();
    for (int i = base + tid; i < end; i += 256) {
        int pk = ebuf[i];
        int ldst = pk >> 14, src = pk & 16383;
        int p = atomicAdd(&cur[ldst], 1);
        csrc[p] = src;
        cw[p] = dinv[src] * dloc[ldst];
    }
}

// Y = X @ W, register-tiled. Block: 256 thr, 32 rows x 128 cols; 4x4 acc.
__global__ __launch_bounds__(256) void k_gemm(const float* __restrict__ X,
                                              const float* __restrict__ W,
                                              float* __restrict__ Y, int nrows) {
    __shared__ float sX[TKC * 36];       // 4.6 KB
    __shared__ float sW[32 * 132];       // 16.9 KB
    int tid = threadIdx.x;
    int rg = tid & 7;                    // rows rg*4 .. rg*4+3
    int cg = tid >> 3;                   // cols cg*4 .. cg*4+3 (0..31)
    int m0 = blockIdx.x * TM;
    float acc[4][4] = {{0.f}};
    for (int kc = 0; kc < NF / TKC; ++kc) {
        int k0 = kc * TKC;
        {   // stage X^T (one float4 per thread)
            int row = tid >> 3, kq = tid & 7;
            int mm = m0 + row; if (mm > nrows - 1) mm = nrows - 1;
            float4 v = *(const float4*)(X + (size_t)mm * NF + k0 + kq * 4);
            sX[(kq * 4 + 0) * 36 + row] = v.x;
            sX[(kq * 4 + 1) * 36 + row] = v.y;
            sX[(kq * 4 + 2) * 36 + row] = v.z;
            sX[(kq * 4 + 3) * 36 + row] = v.w;
        }
#pragma unroll
        for (int j = 0; j < 4; ++j) {    // stage W panels (4 float4 per thread)
            int idx = tid + 256 * j;
            int k = idx >> 5, cq = idx & 31;
            float4 v = *(const float4*)(W + (size_t)(k0 + k) * NF + cq * 4);
            *(float4*)(sW + cq * 132 + k * 4) = v;
        }
        __syncthreads();
#pragma unroll 8
        for (int k = 0; k < TKC; ++k) {
            float4 xf = *(const float4*)(sX + k * 36 + rg * 4);
            float4 wf = *(const float4*)(sW + cg * 132 + k * 4);
            acc[0][0] = fmaf(xf.x, wf.x, acc[0][0]);
            acc[0][1] = fmaf(xf.x, wf.y, acc[0][1]);
            acc[0][2] = fmaf(xf.x, wf.z, acc[0][2]);
            acc[0][3] = fmaf(xf.x, wf.w, acc[0][3]);
            acc[1][0] = fmaf(xf.y, wf.x, acc[1][0]);
            acc[1][1] = fmaf(xf.y, wf.y, acc[1][1]);
            acc[1][2] = fmaf(xf.y, wf.z, acc[1][2]);
            acc[1][3] = fmaf(xf.y, wf.w, acc[1][3]);
            acc[2][0] = fmaf(xf.z, wf.x, acc[2][0]);
            acc[2][1] = fmaf(xf.z, wf.y, acc[2][1]);
            acc[2][2] = fmaf(xf.z, wf.z, acc[2][2]);
            acc[2][3] = fmaf(xf.z, wf.w, acc[2][3]);
            acc[3][0] = fmaf(xf.w, wf.x, acc[3][0]);
            acc[3][1] = fmaf(xf.w, wf.y, acc[3][1]);
            acc[3][2] = fmaf(xf.w, wf.z, acc[3][2]);
            acc[3][3] = fmaf(xf.w, wf.w, acc[3][3]);
        }
        __syncthreads();
    }
#pragma unroll
    for (int r = 0; r < 4; ++r) {
        int m = m0 + rg * 4 + r;
        if (m < nrows)
            *(float4*)(Y + (size_t)m * NF + cg * 4) =
                make_float4(acc[r][0], acc[r][1], acc[r][2], acc[r][3]);
    }
}

// OUT[n] = relu( sum_e cw[e]*XW[csrc[e]] + XW[n]*dinv[n]^2 + bias )
// One wave per node; half-wave per edge; float4 per lane; unroll-4 per half
// -> 8 independent 512B row reads in flight per wave. csrc/cw are linear
// broadcast loads (no random dinv fetch in the hot loop).
__global__ __launch_bounds__(256) void k_gather(const float* __restrict__ XW,
                                                const int* __restrict__ off,
                                                const int* __restrict__ csrc,
                                                const float* __restrict__ cw,
                                                const float* __restrict__ dinv,
                                                const float* __restrict__ bias,
                                                float* __restrict__ OUT) {
    int wid = threadIdx.x >> 6, lane = threadIdx.x & 63;
    int half = lane >> 5;
    int c4 = lane & 31;
    int n = blockIdx.x * 4 + wid;
    if (n >= NN) return;
    int beg = off[n], end = off[n + 1];
    float din = dinv[n];
    float4 acc = make_float4(0.f, 0.f, 0.f, 0.f);
    int e = beg + half;
    for (; e + 6 < end; e += 8) {
        int s0 = csrc[e],     s1 = csrc[e + 2];
        int s2 = csrc[e + 4], s3 = csrc[e + 6];
        float w0 = cw[e],     w1 = cw[e + 2];
        float w2 = cw[e + 4], w3 = cw[e + 6];
        float4 v0 = ((const float4*)(XW + (size_t)s0 * NF))[c4];
        float4 v1 = ((const float4*)(XW + (size_t)s1 * NF))[c4];
        float4 v2 = ((const float4*)(XW + (size_t)s2 * NF))[c4];
        float4 v3 = ((const float4*)(XW + (size_t)s3 * NF))[c4];
        acc.x = fmaf(v0.x, w0, acc.x); acc.y = fmaf(v0.y, w0, acc.y);
        acc.z = fmaf(v0.z, w0, acc.z); acc.w = fmaf(v0.w, w0, acc.w);
        acc.x = fmaf(v1.x, w1, acc.x); acc.y = fmaf(v1.y, w1, acc.y);
        acc.z = fmaf(v1.z, w1, acc.z); acc.w = fmaf(v1.w, w1, acc.w);
        acc.x = fmaf(v2.x, w2, acc.x); acc.y = fmaf(v2.y, w2, acc.y);
        acc.z = fmaf(v2.z, w2, acc.z); acc.w = fmaf(v2.w, w2, acc.w);
        acc.x = fmaf(v3.x, w3, acc.x); acc.y = fmaf(v3.y, w3, acc.y);
        acc.z = fmaf(v3.z, w3, acc.z); acc.w = fmaf(v3.w, w3, acc.w);
    }
    for (; e < end; e += 2) {
        int s = csrc[e];
        float w = cw[e];
        float4 v = ((const float4*)(XW + (size_t)s * NF))[c4];
        acc.x = fmaf(v.x, w, acc.x); acc.y = fmaf(v.y, w, acc.y);
        acc.z = fmaf(v.z, w, acc.z); acc.w = fmaf(v.w, w, acc.w);
    }
    acc.x += __shfl_xor(acc.x, 32);
    acc.y += __shfl_xor(acc.y, 32);
    acc.z += __shfl_xor(acc.z, 32);
    acc.w += __shfl_xor(acc.w, 32);
    if (half == 0) {
        float4 sv = ((const float4*)(XW + (size_t)n * NF))[c4];
        float4 bb = ((const float4*)bias)[c4];
        float d2 = din * din;
        float4 o;
        o.x = fmaxf(fmaf(sv.x, d2, acc.x) + bb.x, 0.f);
        o.y = fmaxf(fmaf(sv.y, d2, acc.y) + bb.y, 0.f);
        o.z = fmaxf(fmaf(sv.z, d2, acc.z) + bb.z, 0.f);
        o.w = fmaxf(fmaf(sv.w, d2, acc.w) + bb.w, 0.f);
        ((float4*)(OUT + (size_t)n * NF))[c4] = o;
    }
}

// Fused global-mean-pool + final linear (batch is sorted -> contiguous ranges).
__global__ __launch_bounds__(256) void k_poolfin(const float* __restrict__ H,
                                                 const void* __restrict__ batch,
                                                 const float* __restrict__ Wl,
                                                 const float* __restrict__ bl,
                                                 float* __restrict__ out) {
    int is64 = detect64((const int*)batch, NN / 2);
    __shared__ int sb[2];
    __shared__ float4 part[256];
    __shared__ float pooled[NF];
    int g = blockIdx.x;
    int tid = threadIdx.x;
    if (tid < 2) {
        int target = g + tid;                 // lower_bound(batch, target)
        int lo = 0, hi = NN;
        while (lo < hi) {
            int mid = (lo + hi) >> 1;
            if (ld_idx(batch, mid, is64) < target) lo = mid + 1; else hi = mid;
        }
        sb[tid] = lo;
    }
    __syncthreads();
    int beg = sb[0], end = sb[1];
    int c4 = tid & 31, r = tid >> 5;          // 8 rows in flight
    float4 acc = make_float4(0.f, 0.f, 0.f, 0.f);
    for (int n = beg + r; n < end; n += 8) {
        float4 v = ((const float4*)(H + (size_t)n * NF))[c4];
        acc.x += v.x; acc.y += v.y; acc.z += v.z; acc.w += v.w;
    }
    part[tid] = acc;
    __syncthreads();
    if (tid < 32) {
        float4 s = part[tid];
#pragma unroll
        for (int j = 1; j < 8; j++) {
            float4 p = part[tid + 32 * j];
            s.x += p.x; s.y += p.y; s.z += p.z; s.w += p.w;
        }
        float ic = 1.0f / fmaxf((float)(end - beg), 1.0f);
        pooled[tid * 4 + 0] = s.x * ic;
        pooled[tid * 4 + 1] = s.y * ic;
        pooled[tid * 4 + 2] = s.z * ic;
        pooled[tid * 4 + 3] = s.w * ic;
    }
    __syncthreads();
    if (tid < NC) {
        float a = bl[tid];
#pragma unroll 8
        for (int k = 0; k < NF; k++)
            a = fmaf(pooled[k], Wl[k * NC + tid], a);
        out[g * NC + tid] = a;
    }
}

extern "C" void kernel_launch(void* const* d_in, const int* in_sizes, int n_in,
                              void* d_out, int out_size, void* d_ws, size_t ws_size,
                              hipStream_t stream) {
    const float* x  = (const float*)d_in[0];
    const void*  ei = d_in[1];
    const void*  bt = d_in[2];
    const float* W1 = (const float*)d_in[3];
    const float* b1 = (const float*)d_in[4];
    const float* W2 = (const float*)d_in[5];
    const float* b2 = (const float*)d_in[6];
    const float* Wl = (const float*)d_in[7];
    const float* bl = (const float*)d_in[8];

    char* ws = (char*)d_ws;
    int*   coff  = (int*)(ws + 0);
    int*   bbase = (int*)(ws + 40016);
    int*   btot  = (int*)(ws + 41040);
    float* dinv  = (float*)(ws + 42064);
    int*   csrc  = (int*)(ws + 82064);
    float* cw    = (float*)(ws + 2642064);
    float* bufA  = (float*)(ws + 5202064);
    float* bufB  = (float*)(ws + 10322064);
    int*   bh    = (int*)bufA;     // 512 KB scratch, dead before k_gemm #1
    int*   ebuf  = (int*)bufB;     // 2.56 MB scratch, dead before k_gather #1

    k_hist  <<<G1, 256, 0, stream>>>(ei, bh);
    k_bscan1<<<(NB + 3) / 4, 256, 0, stream>>>(bh, btot);
    k_bscan2<<<1, 256, 0, stream>>>(btot, bbase);
    k_bucket<<<G1, 256, 0, stream>>>(ei, bh, bbase, ebuf);
    k_deg   <<<NB, 256, 0, stream>>>(ebuf, bbase, dinv);
    k_csr   <<<NB, 256, 0, stream>>>(ebuf, bbase, dinv, coff, csrc, cw);

    k_gemm<<<(NN + TM - 1) / TM, 256, 0, stream>>>(x, W1, bufA, NN);
    k_gather<<<(NN + 3) / 4, 256, 0, stream>>>(bufA, coff, csrc, cw, dinv, b1, bufB);
    k_gemm<<<(NN + TM - 1) / TM, 256, 0, stream>>>(bufB, W2, bufA, NN);
    k_gather<<<(NN + 3) / 4, 256, 0, stream>>>(bufA, coff, csrc, cw, dinv, b2, bufB);

    k_poolfin<<<NG, 256, 0, stream>>>(bufB, bt, Wl, bl, (float*)d_out);
}